// Round 4
// baseline (252.713 us; speedup 1.0000x reference)
//
#include <hip/hip_runtime.h>
#include <hip/hip_fp16.h>

#define TT 256
#define DD 128
#define NEG -30000.0f

typedef __attribute__((ext_vector_type(4))) float f32x4;
typedef __attribute__((ext_vector_type(8))) _Float16 f16x8;
typedef unsigned int u32;
typedef __attribute__((ext_vector_type(4))) u32 u32x4;
typedef unsigned short u16;

__device__ __forceinline__ u16 tof16(float v) {
  return __builtin_bit_cast(u16, (_Float16)v);
}
__device__ __forceinline__ u32 pkf16(float lo, float hi) {
  return (u32)tof16(lo) | ((u32)tof16(hi) << 16);
}

// XOR swizzle on 16B chunks within a row: rows r and r+8 alias (2-way, free).
__device__ __forceinline__ int swz3(int row, int c) {
  return c ^ ((row ^ (row >> 3)) & 7);
}
__device__ __forceinline__ int offR256(int row, int c) {   // [*][128] f16 tile
  return (row << 8) | (swz3(row, c) << 4);
}
__device__ __forceinline__ int offR512(int row, int c) {   // [*][256] f16 tile
  return (row << 9) | (swz3(row, c) << 4);
}
__device__ __forceinline__ int offR256h(int row, int col) {
  return (row << 8) | (swz3(row, col >> 3) << 4) | ((col & 7) << 1);
}
__device__ __forceinline__ int offR512h(int row, int col) {
  return (row << 9) | (swz3(row, col >> 3) << 4) | ((col & 7) << 1);
}

__device__ __forceinline__ f32x4 mfma16(f16x8 a, f16x8 b, f32x4 c) {
  return __builtin_amdgcn_mfma_f32_16x16x32_f16(a, b, c, 0, 0, 0);
}

// ---------------- precompute: MT[d'][d] = M[d][d'] = sum_e Wq[e][d]Wk[e][d'];
// WvB = f16(Wv); m0[d'] = sum_e bq[e] Wk[e][d']
__global__ void precompute_k(const float* __restrict__ Wk, const float* __restrict__ Wq,
                             const float* __restrict__ bq, const float* __restrict__ Wv,
                             u16* __restrict__ MT, u16* __restrict__ WvB, float* __restrict__ m0) {
  int dp = blockIdx.x;
  int d  = threadIdx.x;
  float acc = 0.f;
  for (int e = 0; e < DD; ++e) acc = fmaf(Wq[e*DD + d], Wk[e*DD + dp], acc);
  MT[dp*DD + d] = tof16(acc);
  WvB[dp*DD + d] = tof16(Wv[dp*DD + d]);
  if (dp == 0) {
    float a0 = 0.f;
    for (int e = 0; e < DD; ++e) a0 = fmaf(bq[e], Wk[e*DD + d], a0);
    m0[d] = a0;
  }
}

// ---------------- per-q-tile: S^T tiles = X·A^T, causal mask, softmax, P -> B-frags
__device__ __forceinline__ void attn_sub(int qt, u32x4 (&pf)[8], float& lsum,
                                         const char* bufX, const char* bufA,
                                         int l15, int g) {
  const int nkt = qt + 1;
  const int nch = (nkt + 1) >> 1;
  #pragma unroll
  for (int c = 0; c < 8; ++c) { u32x4 z = {0u,0u,0u,0u}; pf[c] = z; }
  f16x8 bA[4];
  #pragma unroll
  for (int kc = 0; kc < 4; ++kc)
    bA[kc] = *(const f16x8*)(bufA + offR256(qt*16 + l15, 4*kc + g));
  f32x4 sacc[16];
  #pragma unroll
  for (int kt = 0; kt < 16; ++kt) { f32x4 z = {NEG, NEG, NEG, NEG}; sacc[kt] = z; }
  #pragma unroll
  for (int kt = 0; kt < 16; ++kt) {
    if (kt < nkt) {
      f32x4 acc = {0.f, 0.f, 0.f, 0.f};
      #pragma unroll
      for (int kc = 0; kc < 4; ++kc) {
        f16x8 aX = *(const f16x8*)(bufX + offR256(kt*16 + l15, 4*kc + g));
        acc = mfma16(aX, bA[kc], acc);
      }
      if (kt == nkt - 1) {            // diagonal tile: keep k_local <= q_local
        #pragma unroll
        for (int j = 0; j < 4; ++j)
          if (g*4 + j > l15) acc[j] = NEG;
      }
      sacc[kt] = acc;
    }
  }
  float mx = NEG;
  #pragma unroll
  for (int kt = 0; kt < 16; ++kt) if (kt < nkt) {
    #pragma unroll
    for (int j = 0; j < 4; ++j) mx = fmaxf(mx, sacc[kt][j]);
  }
  mx = fmaxf(mx, __shfl_xor(mx, 16));
  mx = fmaxf(mx, __shfl_xor(mx, 32));
  float sum = 0.f;
  #pragma unroll
  for (int kt = 0; kt < 16; ++kt) if (kt < nkt) {
    #pragma unroll
    for (int j = 0; j < 4; ++j) {
      float p = __expf(sacc[kt][j] - mx);
      sacc[kt][j] = p;
      sum += p;
    }
  }
  sum += __shfl_xor(sum, 16);
  sum += __shfl_xor(sum, 32);
  lsum = sum;
  // P^T regs (k=kt*16+g*4+j, q=l15) -> PV B-frag (lane needs P[c*32+g*8+j][l15])
  #pragma unroll
  for (int c = 0; c < 8; ++c) {
    if (c < nch) {
      u32 p00 = pkf16(sacc[2*c][0], sacc[2*c][1]);
      u32 p01 = pkf16(sacc[2*c][2], sacc[2*c][3]);
      u32 p10 = 0u, p11 = 0u;
      if (2*c + 1 < nkt) {
        p10 = pkf16(sacc[2*c+1][0], sacc[2*c+1][1]);
        p11 = pkf16(sacc[2*c+1][2], sacc[2*c+1][3]);
      }
      u32x4 w;
      #pragma unroll
      for (int wd = 0; wd < 4; ++wd) {
        int src = l15 + 16*((2*g + (wd >> 1)) & 3);
        u32 lo = (u32)__shfl((int)((wd & 1) ? p01 : p00), src, 64);
        u32 hi = (u32)__shfl((int)((wd & 1) ? p11 : p10), src, 64);
        w[wd] = (g >> 1) ? hi : lo;
      }
      pf[c] = w;
    }
  }
}

// ---------------- per-q-tile epilogue: O^T = VT·P, normalize, +bv, store
__device__ __forceinline__ void out_sub(int qt, const u32x4 (&pf)[8], float lsum,
                                        const char* bufVT, const float* __restrict__ bvg,
                                        float* __restrict__ outb, int l15, int g) {
  const int nch = (qt + 2) >> 1;
  const float inv = 1.f / lsum;
  #pragma unroll
  for (int et = 0; et < 8; ++et) {
    f32x4 acc = {0.f, 0.f, 0.f, 0.f};
    #pragma unroll
    for (int c = 0; c < 8; ++c) {
      if (c < nch) {
        f16x8 aV = *(const f16x8*)(bufVT + offR512(et*16 + l15, 4*c + g));
        f16x8 pb = __builtin_bit_cast(f16x8, pf[c]);
        acc = mfma16(aV, pb, acc);
      }
    }
    const int q  = qt*16 + l15;
    const int e0 = et*16 + g*4;
    f32x4 bvv = *(const f32x4*)(bvg + e0);
    f32x4 o;
    #pragma unroll
    for (int j = 0; j < 4; ++j) o[j] = acc[j]*inv + bvv[j];
    *(f32x4*)(outb + q*DD + e0) = o;
  }
}

// ---------------- fused head: grid 256, 2 batches/block pipelined, 16 waves, 160KB LDS
__global__ __launch_bounds__(1024, 4)
void head_fused(const float* __restrict__ x, const u16* __restrict__ MTg,
                const u16* __restrict__ Wvg, const float* __restrict__ m0g,
                const float* __restrict__ bvg, float* __restrict__ out) {
  extern __shared__ char lds[];
  char* bufX = lds;            // X [256][128] f16 swizzled (64 KB)
  char* bufA = lds + 65536;    // A [256][128] -> reused as VT [128][256] (64 KB)
  char* bufW = lds + 131072;   // MT [128][128] f16 swizzled (32 KB), staged once

  const int tid  = threadIdx.x;
  const int wave = tid >> 6;
  const int lane = tid & 63;
  const int l15  = lane & 15;
  const int g    = lane >> 4;

  // Phase 0: defensive zero-init of all 160 KB (one-time)
  {
    u32x4* p = (u32x4*)lds;
    #pragma unroll
    for (int i = 0; i < 10; ++i) { u32x4 z = {0u,0u,0u,0u}; p[tid + i*1024] = z; }
  }
  __syncthreads();

  // Phase 1: stage MT -> bufW (once) and X(b0) -> bufX (f32->f16, swizzled)
  #pragma unroll
  for (int i = 0; i < 2; ++i) {
    int chunk = tid + i*1024;
    int row = chunk >> 4, c = chunk & 15;
    u32x4 v = *(const u32x4*)((const char*)MTg + row*256 + c*16);
    *(u32x4*)(bufW + offR256(row, c)) = v;
  }
  {
    const float* xb = x + (size_t)blockIdx.x * (TT*DD);
    #pragma unroll
    for (int i = 0; i < 4; ++i) {
      int chunk = tid + i*1024;
      int row = chunk >> 4, c = chunk & 15;
      const float* p = xb + row*DD + c*8;
      f32x4 v0 = *(const f32x4*)p;
      f32x4 v1 = *(const f32x4*)(p + 4);
      u32x4 w;
      w[0] = pkf16(v0[0], v0[1]);
      w[1] = pkf16(v0[2], v0[3]);
      w[2] = pkf16(v1[0], v1[1]);
      w[3] = pkf16(v1[2], v1[3]);
      *(u32x4*)(bufX + offR256(row, c)) = w;
    }
  }
  __syncthreads();

  f32x4 px[8];   // prefetch registers for batch b1's X tile (32 VGPR)

  #pragma unroll
  for (int bi = 0; bi < 2; ++bi) {
    const int b = blockIdx.x + (bi << 8);

    if (bi == 1) {
      // write prefetched X(b1) -> bufX (bufX free since P4(b0) barrier; P5 doesn't read it)
      #pragma unroll
      for (int i = 0; i < 4; ++i) {
        int chunk = tid + i*1024;
        int row = chunk >> 4, c = chunk & 15;
        f32x4 v0 = px[2*i], v1 = px[2*i + 1];
        u32x4 w;
        w[0] = pkf16(v0[0], v0[1]);
        w[1] = pkf16(v0[2], v0[3]);
        w[2] = pkf16(v1[0], v1[1]);
        w[3] = pkf16(v1[2], v1[3]);
        *(u32x4*)(bufX + offR256(row, c)) = w;
      }
      __syncthreads();
    }

    // Phase 2: A = X·MT^T(+m0) -> bufA. Wave w handles q-tile w.
    {
      const int qt = wave;
      f16x8 aX[4];
      #pragma unroll
      for (int kc = 0; kc < 4; ++kc)
        aX[kc] = *(const f16x8*)(bufX + offR256(qt*16 + l15, 4*kc + g));
      #pragma unroll
      for (int nt = 0; nt < 8; ++nt) {
        f32x4 acc = {0.f, 0.f, 0.f, 0.f};
        #pragma unroll
        for (int kc = 0; kc < 4; ++kc) {
          f16x8 bM = *(const f16x8*)(bufW + offR256(nt*16 + l15, 4*kc + g));
          acc = mfma16(aX[kc], bM, acc);
        }
        float m0v = m0g[nt*16 + l15];
        #pragma unroll
        for (int j = 0; j < 4; ++j)
          *(u16*)(bufA + offR256h(qt*16 + g*4 + j, nt*16 + l15)) = tof16(acc[j] + m0v);
      }
    }
    __syncthreads();

    // Phase 3: wave w: S^T for q-tile w + softmax + P-frags (in regs)
    u32x4 pf[8];
    float ls;
    attn_sub(wave, pf, ls, bufX, bufA, l15, g);
    __syncthreads();

    // Prefetch X(b1): issue global loads now; latency hides under P4+P5 compute.
    if (bi == 0) {
      const float* xb1 = x + (size_t)(blockIdx.x + 256) * (TT*DD);
      #pragma unroll
      for (int i = 0; i < 4; ++i) {
        int chunk = tid + i*1024;
        int row = chunk >> 4, c = chunk & 15;
        const float* p = xb1 + row*DD + c*8;
        px[2*i]     = *(const f32x4*)p;
        px[2*i + 1] = *(const f32x4*)(p + 4);
      }
    }

    // Phase 4: VT = Wv·X^T -> bufA as [128][256]. Wave w handles k-tile w.
    // Wv A-frags straight from global (32KB, L1-resident).
    {
      const int kt = wave;
      f16x8 bX[4];
      #pragma unroll
      for (int kc = 0; kc < 4; ++kc)
        bX[kc] = *(const f16x8*)(bufX + offR256(kt*16 + l15, 4*kc + g));
      #pragma unroll
      for (int et = 0; et < 8; ++et) {
        f32x4 acc = {0.f, 0.f, 0.f, 0.f};
        #pragma unroll
        for (int kc = 0; kc < 4; ++kc) {
          f16x8 aW = *(const f16x8*)(Wvg + (et*16 + l15)*DD + kc*32 + g*8);
          acc = mfma16(aW, bX[kc], acc);
        }
        #pragma unroll
        for (int j = 0; j < 4; ++j)
          *(u16*)(bufA + offR512h(et*16 + g*4 + j, kt*16 + l15)) = tof16(acc[j]);
      }
    }
    __syncthreads();

    // Phase 5: O = P·V / l + bv (stores overlap next batch's compute)
    float* outb = out + (size_t)b * (TT*DD);
    out_sub(wave, pf, ls, bufA, bvg, outb, l15, g);
  }
}

extern "C" void kernel_launch(void* const* d_in, const int* in_sizes, int n_in,
                              void* d_out, int out_size, void* d_ws, size_t ws_size,
                              hipStream_t stream) {
  (void)in_sizes; (void)n_in; (void)out_size; (void)ws_size;
  const float* x  = (const float*)d_in[0];
  const float* Wk = (const float*)d_in[1];
  // d_in[2] = bk: contributes only per-q-row constants to scores -> dropped by softmax
  const float* Wq = (const float*)d_in[3];
  const float* bq = (const float*)d_in[4];
  const float* Wv = (const float*)d_in[5];
  const float* bv = (const float*)d_in[6];

  char* ws = (char*)d_ws;
  u16*   MT  = (u16*)ws;               // 32 KB
  u16*   WvB = (u16*)(ws + 32768);     // 32 KB
  float* m0  = (float*)(ws + 65536);   // 512 B

  (void)hipFuncSetAttribute((const void*)head_fused,
                            hipFuncAttributeMaxDynamicSharedMemorySize, 163840);

  precompute_k<<<128, 128, 0, stream>>>(Wk, Wq, bq, Wv, MT, WvB, m0);
  head_fused<<<256, 1024, 163840, stream>>>(x, MT, WvB, m0, bv, (float*)d_out);
}

// Round 5
// 191.866 us; speedup vs baseline: 1.3171x; 1.3171x over previous
//
#include <hip/hip_runtime.h>
#include <hip/hip_fp16.h>

#define TT 256
#define DD 128
#define NEG -30000.0f

typedef __attribute__((ext_vector_type(4))) float f32x4;
typedef __attribute__((ext_vector_type(8))) _Float16 f16x8;
typedef unsigned int u32;
typedef __attribute__((ext_vector_type(4))) u32 u32x4;
typedef unsigned short u16;

__device__ __forceinline__ u16 tof16(float v) {
  return __builtin_bit_cast(u16, (_Float16)v);
}
__device__ __forceinline__ u32 pkf16(float lo, float hi) {
  return (u32)tof16(lo) | ((u32)tof16(hi) << 16);
}
__device__ __forceinline__ f32x4 mfma16(f16x8 a, f16x8 b, f32x4 c) {
  return __builtin_amdgcn_mfma_f32_16x16x32_f16(a, b, c, 0, 0, 0);
}

// Transpose-convert 8 D-layout f32x4 tiles to 4 B-frag u32x4 words.
// src[t] lane(l15,g): V[row=t*16+g*4+j][col=l15]  ->  dst[p] lane(l15,g):
// packed f16 V^T[col=l15][row=p*32+g*8+0..7]. Same shfl net as pf (verified).
__device__ __forceinline__ void conv8(const f32x4* src, u32x4* dst, int l15, int g) {
  #pragma unroll
  for (int p = 0; p < 4; ++p) {
    u32 p00 = pkf16(src[2*p][0], src[2*p][1]);
    u32 p01 = pkf16(src[2*p][2], src[2*p][3]);
    u32 p10 = pkf16(src[2*p+1][0], src[2*p+1][1]);
    u32 p11 = pkf16(src[2*p+1][2], src[2*p+1][3]);
    u32x4 w;
    #pragma unroll
    for (int wd = 0; wd < 4; ++wd) {
      int srcl = l15 + 16*((2*g + (wd >> 1)) & 3);
      u32 lo = (u32)__shfl((int)((wd & 1) ? p01 : p00), srcl, 64);
      u32 hi = (u32)__shfl((int)((wd & 1) ? p11 : p10), srcl, 64);
      w[wd] = (g >> 1) ? hi : lo;
    }
    dst[p] = w;
  }
}

// ---------------- precompute: MT[d'][d] = M[d][d'] = sum_e Wq[e][d]Wk[e][d'];
// WvB = f16(Wv); m0[d] = sum_e bq[e]Wk[e][d]
__global__ void precompute_k(const float* __restrict__ Wk, const float* __restrict__ Wq,
                             const float* __restrict__ bq, const float* __restrict__ Wv,
                             u16* __restrict__ MT, u16* __restrict__ WvB, float* __restrict__ m0) {
  int dp = blockIdx.x;
  int d  = threadIdx.x;
  float acc = 0.f;
  for (int e = 0; e < DD; ++e) acc = fmaf(Wq[e*DD + d], Wk[e*DD + dp], acc);
  MT[dp*DD + d] = tof16(acc);
  WvB[dp*DD + d] = tof16(Wv[dp*DD + d]);
  if (dp == 0) {
    float a0 = 0.f;
    for (int e = 0; e < DD; ++e) a0 = fmaf(bq[e], Wk[e*DD + d], a0);
    m0[d] = a0;
  }
}

// ---------------- fused head: 2048 blocks x 256 thr, no LDS, no barriers.
// Block (b, s): wave w handles q-tile qt = 4w + s of batch b.
__global__ __launch_bounds__(256, 4)
void head_fused(const float* __restrict__ x, const u16* __restrict__ MTg,
                const u16* __restrict__ Wvh, const float* __restrict__ m0g,
                const float* __restrict__ bvg, float* __restrict__ out) {
  const int tid  = threadIdx.x;
  const int wave = tid >> 6;
  const int lane = tid & 63;
  const int l15  = lane & 15;
  const int g    = lane >> 4;

  // Bijective XCD swizzle: all 4 sub-blocks of a batch land on one XCD.
  const int bid = blockIdx.x;
  const int L   = (bid & 7) * 256 + (bid >> 3);
  const int b   = L >> 2;
  const int s   = L & 3;
  const int qt  = (wave << 2) | s;

  const float* xb = x + (size_t)b * (TT*DD);
  const int nkt = qt + 1;
  const int nch = (nkt + 1) >> 1;

  // ---- Phase A: A'-strip in regs. Aacc[dt] lane: A'[q=l15][d'=dt*16+g*4+j]
  f16x8 bXq[4];   // X q-strip B-frags: row qt*16+l15, cols kc*32+g*8..+7
  #pragma unroll
  for (int kc = 0; kc < 4; ++kc) {
    const float* p = xb + (qt*16 + l15)*DD + kc*32 + g*8;
    f32x4 v0 = *(const f32x4*)p, v1 = *(const f32x4*)(p + 4);
    u32x4 w;
    w[0] = pkf16(v0[0], v0[1]); w[1] = pkf16(v0[2], v0[3]);
    w[2] = pkf16(v1[0], v1[1]); w[3] = pkf16(v1[2], v1[3]);
    bXq[kc] = __builtin_bit_cast(f16x8, w);
  }
  f32x4 Aacc[8];
  #pragma unroll
  for (int dt = 0; dt < 8; ++dt) {
    f32x4 acc = {0.f, 0.f, 0.f, 0.f};
    #pragma unroll
    for (int kc = 0; kc < 4; ++kc) {
      f16x8 aM = *(const f16x8*)(MTg + (dt*16 + l15)*DD + kc*32 + g*8);
      acc = mfma16(aM, bXq[kc], acc);
    }
    f32x4 m0v = *(const f32x4*)(m0g + dt*16 + g*4);
    #pragma unroll
    for (int j = 0; j < 4; ++j) acc[j] += m0v[j];
    Aacc[dt] = acc;
  }
  u32x4 bAw[4];
  conv8(Aacc, bAw, l15, g);   // bA[kc]: A'[q=l15][d'=kc*32+g*8..+7] f16

  // ---- Phase S: S^T tiles = X . A'^T  (D[k][q]), causal mask, softmax
  f32x4 sacc[16];
  #pragma unroll
  for (int kt = 0; kt < 16; ++kt) { f32x4 z = {NEG, NEG, NEG, NEG}; sacc[kt] = z; }
  #pragma unroll
  for (int kt = 0; kt < 16; ++kt) {
    if (kt < nkt) {
      f32x4 acc = {0.f, 0.f, 0.f, 0.f};
      #pragma unroll
      for (int kc = 0; kc < 4; ++kc) {
        const float* p = xb + (kt*16 + l15)*DD + kc*32 + g*8;
        f32x4 v0 = *(const f32x4*)p, v1 = *(const f32x4*)(p + 4);
        u32x4 w;
        w[0] = pkf16(v0[0], v0[1]); w[1] = pkf16(v0[2], v0[3]);
        w[2] = pkf16(v1[0], v1[1]); w[3] = pkf16(v1[2], v1[3]);
        acc = mfma16(__builtin_bit_cast(f16x8, w),
                     __builtin_bit_cast(f16x8, bAw[kc]), acc);
      }
      if (kt == nkt - 1) {            // diagonal tile: keep k_local <= q_local
        #pragma unroll
        for (int j = 0; j < 4; ++j)
          if (g*4 + j > l15) acc[j] = NEG;
      }
      sacc[kt] = acc;
    }
  }
  float mx = NEG;
  #pragma unroll
  for (int kt = 0; kt < 16; ++kt) if (kt < nkt) {
    #pragma unroll
    for (int j = 0; j < 4; ++j) mx = fmaxf(mx, sacc[kt][j]);
  }
  mx = fmaxf(mx, __shfl_xor(mx, 16));
  mx = fmaxf(mx, __shfl_xor(mx, 32));
  float sum = 0.f;
  #pragma unroll
  for (int kt = 0; kt < 16; ++kt) if (kt < nkt) {
    #pragma unroll
    for (int j = 0; j < 4; ++j) {
      float p = __expf(sacc[kt][j] - mx);
      sacc[kt][j] = p;
      sum += p;
    }
  }
  sum += __shfl_xor(sum, 16);
  sum += __shfl_xor(sum, 32);
  const float inv = 1.f / sum;

  // ---- pf: P^T regs -> PV B-frags (lane: P[k=c*32+g*8+0..7][q=l15] f16)
  u32x4 pf[8];
  #pragma unroll
  for (int c = 0; c < 8; ++c) { u32x4 z = {0u,0u,0u,0u}; pf[c] = z; }
  #pragma unroll
  for (int c = 0; c < 8; ++c) {
    if (c < nch) {
      u32 p00 = pkf16(sacc[2*c][0], sacc[2*c][1]);
      u32 p01 = pkf16(sacc[2*c][2], sacc[2*c][3]);
      u32 p10 = 0u, p11 = 0u;
      if (2*c + 1 < nkt) {
        p10 = pkf16(sacc[2*c+1][0], sacc[2*c+1][1]);
        p11 = pkf16(sacc[2*c+1][2], sacc[2*c+1][3]);
      }
      u32x4 w;
      #pragma unroll
      for (int wd = 0; wd < 4; ++wd) {
        int srcl = l15 + 16*((2*g + (wd >> 1)) & 3);
        u32 lo = (u32)__shfl((int)((wd & 1) ? p01 : p00), srcl, 64);
        u32 hi = (u32)__shfl((int)((wd & 1) ? p11 : p10), srcl, 64);
        w[wd] = (g >> 1) ? hi : lo;
      }
      pf[c] = w;
    }
  }

  // ---- Phase R: R = X^T . P   (D[d][q], contraction over k)
  // A-frag lane: X[k=c*32+g*8+m][d=dt*16+l15] -> coalesced 16-lane row segments
  f32x4 racc[8];
  #pragma unroll
  for (int dt = 0; dt < 8; ++dt) { f32x4 z = {0.f,0.f,0.f,0.f}; racc[dt] = z; }
  #pragma unroll
  for (int c = 0; c < 8; ++c) {
    if (c < nch) {
      f16x8 pb = __builtin_bit_cast(f16x8, pf[c]);
      const float* pc = xb + (c*32 + g*8)*DD + l15;
      #pragma unroll
      for (int dt = 0; dt < 8; ++dt) {
        u32x4 h;
        #pragma unroll
        for (int m = 0; m < 4; ++m) {
          float a0 = pc[(2*m)*DD     + dt*16];
          float a1 = pc[(2*m + 1)*DD + dt*16];
          h[m] = pkf16(a0, a1);
        }
        racc[dt] = mfma16(__builtin_bit_cast(f16x8, h), pb, racc[dt]);
      }
    }
  }
  u32x4 bRw[4];
  conv8(racc, bRw, l15, g);   // bR[kc]: R^T[q=l15][d=kc*32+g*8..+7] f16

  // ---- Phase O: O^T = Wv . R; normalize + bv; store
  float* outb = out + (size_t)b * (TT*DD);
  #pragma unroll
  for (int et = 0; et < 8; ++et) {
    f32x4 oacc = {0.f, 0.f, 0.f, 0.f};
    #pragma unroll
    for (int kc = 0; kc < 4; ++kc) {
      f16x8 aV = *(const f16x8*)(Wvh + (et*16 + l15)*DD + kc*32 + g*8);
      oacc = mfma16(aV, __builtin_bit_cast(f16x8, bRw[kc]), oacc);
    }
    f32x4 bvv = *(const f32x4*)(bvg + et*16 + g*4);
    f32x4 o;
    #pragma unroll
    for (int j = 0; j < 4; ++j) o[j] = oacc[j]*inv + bvv[j];
    *(f32x4*)(outb + (qt*16 + l15)*DD + et*16 + g*4) = o;
  }
}

extern "C" void kernel_launch(void* const* d_in, const int* in_sizes, int n_in,
                              void* d_out, int out_size, void* d_ws, size_t ws_size,
                              hipStream_t stream) {
  (void)in_sizes; (void)n_in; (void)out_size; (void)ws_size;
  const float* x  = (const float*)d_in[0];
  const float* Wk = (const float*)d_in[1];
  // d_in[2] = bk: contributes only per-q-row constants to scores -> dropped by softmax
  const float* Wq = (const float*)d_in[3];
  const float* bq = (const float*)d_in[4];
  const float* Wv = (const float*)d_in[5];
  const float* bv = (const float*)d_in[6];

  char* ws = (char*)d_ws;
  u16*   MT  = (u16*)ws;               // 32 KB
  u16*   WvB = (u16*)(ws + 32768);     // 32 KB
  float* m0  = (float*)(ws + 65536);   // 512 B

  precompute_k<<<128, 128, 0, stream>>>(Wk, Wq, bq, Wv, MT, WvB, m0);
  head_fused<<<2048, 256, 0, stream>>>(x, MT, WvB, m0, bv, (float*)d_out);
}

// Round 6
// 117.098 us; speedup vs baseline: 2.1581x; 1.6385x over previous
//
#include <hip/hip_runtime.h>
#include <hip/hip_fp16.h>

#define TT 256
#define DD 128
#define NEG -30000.0f

typedef __attribute__((ext_vector_type(4))) float f32x4;
typedef __attribute__((ext_vector_type(8))) _Float16 f16x8;
typedef unsigned int u32;
typedef __attribute__((ext_vector_type(4))) u32 u32x4;
typedef unsigned short u16;

__device__ __forceinline__ u16 tof16(float v) {
  return __builtin_bit_cast(u16, (_Float16)v);
}
__device__ __forceinline__ u32 pkf16(float lo, float hi) {
  return (u32)tof16(lo) | ((u32)tof16(hi) << 16);
}
__device__ __forceinline__ f32x4 mfma16(f16x8 a, f16x8 b, f32x4 c) {
  return __builtin_amdgcn_mfma_f32_16x16x32_f16(a, b, c, 0, 0, 0);
}

// D-layout -> operand-frag repack (lane index/col stays fixed; rows move from
// (t, g*4+j) to packed elements (p, g*8+0..7)). Verified via rounds 2-5.
// src[2P] D-tiles (rows t*16+g*4+j, col l15) -> dst[P] frags: lane(l15,g)
// holds packed f16 of M[col=l15][row=p*32+g*8+0..7].
template<int P>
__device__ __forceinline__ void convN(const f32x4* src, u32x4* dst, int l15, int g) {
  #pragma unroll
  for (int p = 0; p < P; ++p) {
    u32 p00 = pkf16(src[2*p][0], src[2*p][1]);
    u32 p01 = pkf16(src[2*p][2], src[2*p][3]);
    u32 p10 = pkf16(src[2*p+1][0], src[2*p+1][1]);
    u32 p11 = pkf16(src[2*p+1][2], src[2*p+1][3]);
    u32x4 w;
    #pragma unroll
    for (int wd = 0; wd < 4; ++wd) {
      int srcl = l15 + 16*((2*g + (wd >> 1)) & 3);
      u32 lo = (u32)__shfl((int)((wd & 1) ? p01 : p00), srcl, 64);
      u32 hi = (u32)__shfl((int)((wd & 1) ? p11 : p10), srcl, 64);
      w[wd] = (g >> 1) ? hi : lo;
    }
    dst[p] = w;
  }
}

// ---------------- precompute: MT[d'][d] = sum_e Wq[e][d]Wk[e][d']; WvB=f16(Wv);
// m0[d] = sum_e bq[e]Wk[e][d]
__global__ void precompute_k(const float* __restrict__ Wk, const float* __restrict__ Wq,
                             const float* __restrict__ bq, const float* __restrict__ Wv,
                             u16* __restrict__ MT, u16* __restrict__ WvB, float* __restrict__ m0) {
  int dp = blockIdx.x;
  int d  = threadIdx.x;
  float acc = 0.f;
  for (int e = 0; e < DD; ++e) acc = fmaf(Wq[e*DD + d], Wk[e*DD + dp], acc);
  MT[dp*DD + d] = tof16(acc);
  WvB[dp*DD + d] = tof16(Wv[dp*DD + d]);
  if (dp == 0) {
    float a0 = 0.f;
    for (int e = 0; e < DD; ++e) a0 = fmaf(bq[e], Wk[e*DD + d], a0);
    m0[d] = a0;
  }
}

// ---------------- K1: per batch, produce frag-blocked Xh and VT. No LDS/barriers.
// xh[b][kt][kc][g][l15]*16B = Xh[kt*16+l15][kc*32+g*8..+7]
// vt[b][et][c][g][l15]*16B  = VT[et*16+l15][c*32+g*8..+7]  (V = X.Wv^T, bias deferred)
__global__ __launch_bounds__(256, 4)
void proj_vt(const float* __restrict__ x, const u16* __restrict__ WvB,
             char* __restrict__ xh, char* __restrict__ vt) {
  const int tid = threadIdx.x;
  const int w = tid >> 6, lane = tid & 63, l15 = lane & 15, g = lane >> 4;
  const int b = blockIdx.x;
  const float* xb = x + (size_t)b * (TT*DD);
  char* xhb = xh + (size_t)b * 65536;
  char* vtb = vt + (size_t)b * 65536;

  // load + cvt X rows kt = 4w..4w+3; store Xh frags
  f16x8 bX[4][4];
  #pragma unroll
  for (int t = 0; t < 4; ++t) {
    const int kt = 4*w + t;
    #pragma unroll
    for (int kc = 0; kc < 4; ++kc) {
      const float* p = xb + (kt*16 + l15)*DD + kc*32 + g*8;
      f32x4 v0 = *(const f32x4*)p, v1 = *(const f32x4*)(p + 4);
      u32x4 pk;
      pk[0] = pkf16(v0[0], v0[1]); pk[1] = pkf16(v0[2], v0[3]);
      pk[2] = pkf16(v1[0], v1[1]); pk[3] = pkf16(v1[2], v1[3]);
      bX[t][kc] = __builtin_bit_cast(f16x8, pk);
      *(u32x4*)(xhb + kt*4096 + kc*1024 + g*256 + l15*16) = pk;
    }
  }

  // VT: V[k][e] = mfma(A=X rows, B=Wv rows); conv -> VT A-frags; store
  #pragma unroll
  for (int et = 0; et < 8; ++et) {
    f16x8 bWv[4];
    #pragma unroll
    for (int kc = 0; kc < 4; ++kc)
      bWv[kc] = *(const f16x8*)(WvB + (et*16 + l15)*DD + kc*32 + g*8);
    f32x4 vacc[4];
    #pragma unroll
    for (int t = 0; t < 4; ++t) {
      f32x4 acc = {0.f, 0.f, 0.f, 0.f};
      #pragma unroll
      for (int kc = 0; kc < 4; ++kc) acc = mfma16(bX[t][kc], bWv[kc], acc);
      vacc[t] = acc;
    }
    u32x4 dv[2];
    convN<2>(vacc, dv, l15, g);
    #pragma unroll
    for (int p2 = 0; p2 < 2; ++p2)
      *(u32x4*)(vtb + et*8192 + (2*w + p2)*1024 + g*256 + l15*16) = dv[p2];
  }
}

// ---------------- K2: attention. 2048 blocks x 256 thr; wave = one q-tile.
// No LDS, no barriers; all operands are coalesced 16B frag loads from ws (L2/L3).
__global__ __launch_bounds__(256, 4)
void attn_k(const char* __restrict__ xh, const char* __restrict__ vt,
            const u16* __restrict__ MTg, const float* __restrict__ m0g,
            const float* __restrict__ bvg, float* __restrict__ out) {
  const int tid  = threadIdx.x;
  const int wave = tid >> 6, lane = tid & 63, l15 = lane & 15, g = lane >> 4;
  // bijective XCD swizzle; same-batch blocks mostly co-XCD
  const int bid = blockIdx.x;
  const int L   = (bid & 7) * 256 + (bid >> 3);
  const int b   = L >> 2;
  const int s   = L & 3;
  const int qt  = wave*4 + s;          // block covers {s, s+4, s+8, s+12}: balanced
  const int nkt = qt + 1;
  const int nch = (nkt + 1) >> 1;
  const char* xhb = xh + (size_t)b * 65536;

  // ---- Phase A: A'-strip in regs (D[m=d'][n=q]); conv -> B-frags bAw
  f16x8 bXq[4];
  #pragma unroll
  for (int kc = 0; kc < 4; ++kc)
    bXq[kc] = *(const f16x8*)(xhb + qt*4096 + kc*1024 + g*256 + l15*16);
  f32x4 Aacc[8];
  #pragma unroll
  for (int dt = 0; dt < 8; ++dt) {
    f32x4 acc = {0.f, 0.f, 0.f, 0.f};
    #pragma unroll
    for (int kc = 0; kc < 4; ++kc) {
      f16x8 aM = *(const f16x8*)(MTg + (dt*16 + l15)*DD + kc*32 + g*8);
      acc = mfma16(aM, bXq[kc], acc);
    }
    f32x4 m0v = *(const f32x4*)(m0g + dt*16 + g*4);
    #pragma unroll
    for (int j = 0; j < 4; ++j) acc[j] += m0v[j];
    Aacc[dt] = acc;
  }
  u32x4 bAw[4];
  convN<4>(Aacc, bAw, l15, g);

  // ---- Phase S: S^T[k][q] = mfma(A=Xh rows, B=bAw); mask; softmax
  f32x4 sacc[16];
  #pragma unroll
  for (int kt = 0; kt < 16; ++kt) { f32x4 z = {NEG, NEG, NEG, NEG}; sacc[kt] = z; }
  #pragma unroll
  for (int kt = 0; kt < 16; ++kt) {
    if (kt < nkt) {
      f32x4 acc = {0.f, 0.f, 0.f, 0.f};
      #pragma unroll
      for (int kc = 0; kc < 4; ++kc) {
        f16x8 aX = *(const f16x8*)(xhb + kt*4096 + kc*1024 + g*256 + l15*16);
        acc = mfma16(aX, __builtin_bit_cast(f16x8, bAw[kc]), acc);
      }
      if (kt == nkt - 1) {     // diagonal: keep k_local <= q_local
        #pragma unroll
        for (int j = 0; j < 4; ++j)
          if (g*4 + j > l15) acc[j] = NEG;
      }
      sacc[kt] = acc;
    }
  }
  float mx = NEG;
  #pragma unroll
  for (int kt = 0; kt < 16; ++kt) if (kt < nkt) {
    #pragma unroll
    for (int j = 0; j < 4; ++j) mx = fmaxf(mx, sacc[kt][j]);
  }
  mx = fmaxf(mx, __shfl_xor(mx, 16));
  mx = fmaxf(mx, __shfl_xor(mx, 32));
  float sum = 0.f;
  #pragma unroll
  for (int kt = 0; kt < 16; ++kt) if (kt < nkt) {
    #pragma unroll
    for (int j = 0; j < 4; ++j) {
      float p = __expf(sacc[kt][j] - mx);
      sacc[kt][j] = p;
      sum += p;
    }
  }
  sum += __shfl_xor(sum, 16);
  sum += __shfl_xor(sum, 32);
  const float inv = 1.f / sum;

  // ---- pf: P^T regs -> B-frags (lane: P^T[k=c*32+g*8+0..7][q=l15])
  u32x4 pf[8];
  #pragma unroll
  for (int c = 0; c < 8; ++c) { u32x4 z = {0u,0u,0u,0u}; pf[c] = z; }
  #pragma unroll
  for (int c = 0; c < 8; ++c) {
    if (c < nch) {
      u32 p00 = pkf16(sacc[2*c][0], sacc[2*c][1]);
      u32 p01 = pkf16(sacc[2*c][2], sacc[2*c][3]);
      u32 p10 = 0u, p11 = 0u;
      if (2*c + 1 < nkt) {
        p10 = pkf16(sacc[2*c+1][0], sacc[2*c+1][1]);
        p11 = pkf16(sacc[2*c+1][2], sacc[2*c+1][3]);
      }
      u32x4 w;
      #pragma unroll
      for (int wd = 0; wd < 4; ++wd) {
        int srcl = l15 + 16*((2*g + (wd >> 1)) & 3);
        u32 lo = (u32)__shfl((int)((wd & 1) ? p01 : p00), srcl, 64);
        u32 hi = (u32)__shfl((int)((wd & 1) ? p11 : p10), srcl, 64);
        w[wd] = (g >> 1) ? hi : lo;
      }
      pf[c] = w;
    }
  }

  // ---- PV: O^T[e][q] = mfma(A=VT frags, B=pf); normalize + bv; store
  const char* vtb = vt + (size_t)b * 65536;
  float* outb = out + (size_t)b * (TT*DD);
  #pragma unroll
  for (int et = 0; et < 8; ++et) {
    f32x4 oacc = {0.f, 0.f, 0.f, 0.f};
    #pragma unroll
    for (int c = 0; c < 8; ++c) {
      if (c < nch) {
        f16x8 aV = *(const f16x8*)(vtb + et*8192 + c*1024 + g*256 + l15*16);
        oacc = mfma16(aV, __builtin_bit_cast(f16x8, pf[c]), oacc);
      }
    }
    f32x4 bvv = *(const f32x4*)(bvg + et*16 + g*4);
    f32x4 o;
    #pragma unroll
    for (int j = 0; j < 4; ++j) o[j] = oacc[j]*inv + bvv[j];
    *(f32x4*)(outb + (qt*16 + l15)*DD + et*16 + g*4) = o;
  }
}

// ================= fallback (round-2 verified kernel, 100us) =================
__device__ __forceinline__ int swz3(int row, int c) {
  return c ^ ((row ^ (row >> 3)) & 7);
}
__device__ __forceinline__ int offR256(int row, int c) {
  return (row << 8) | (swz3(row, c) << 4);
}
__device__ __forceinline__ int offR512(int row, int c) {
  return (row << 9) | (swz3(row, c) << 4);
}
__device__ __forceinline__ int offR256h(int row, int col) {
  return (row << 8) | (swz3(row, col >> 3) << 4) | ((col & 7) << 1);
}
__device__ __forceinline__ int offR512h(int row, int col) {
  return (row << 9) | (swz3(row, col >> 3) << 4) | ((col & 7) << 1);
}

template<int MAXT, int MAXC>
__device__ __forceinline__ void attn_sub_fb(int qt, u32x4 (&pf)[MAXC], float& lsum,
                                            const char* bufX, const char* bufA,
                                            int l15, int g) {
  const int nkt = qt + 1;
  const int nch = (nkt + 1) >> 1;
  #pragma unroll
  for (int c = 0; c < MAXC; ++c) { u32x4 z = {0u,0u,0u,0u}; pf[c] = z; }
  f16x8 bA[4];
  #pragma unroll
  for (int kc = 0; kc < 4; ++kc)
    bA[kc] = *(const f16x8*)(bufA + offR256(qt*16 + l15, 4*kc + g));
  f32x4 sacc[MAXT];
  #pragma unroll
  for (int kt = 0; kt < MAXT; ++kt) { f32x4 z = {NEG, NEG, NEG, NEG}; sacc[kt] = z; }
  #pragma unroll
  for (int kt = 0; kt < MAXT; ++kt) {
    if (kt < nkt) {
      f32x4 acc = {0.f, 0.f, 0.f, 0.f};
      #pragma unroll
      for (int kc = 0; kc < 4; ++kc) {
        f16x8 aX = *(const f16x8*)(bufX + offR256(kt*16 + l15, 4*kc + g));
        acc = mfma16(aX, bA[kc], acc);
      }
      if (kt == nkt - 1) {
        #pragma unroll
        for (int j = 0; j < 4; ++j)
          if (g*4 + j > l15) acc[j] = NEG;
      }
      sacc[kt] = acc;
    }
  }
  float mx = NEG;
  #pragma unroll
  for (int kt = 0; kt < MAXT; ++kt) if (kt < nkt) {
    #pragma unroll
    for (int j = 0; j < 4; ++j) mx = fmaxf(mx, sacc[kt][j]);
  }
  mx = fmaxf(mx, __shfl_xor(mx, 16));
  mx = fmaxf(mx, __shfl_xor(mx, 32));
  float sum = 0.f;
  #pragma unroll
  for (int kt = 0; kt < MAXT; ++kt) if (kt < nkt) {
    #pragma unroll
    for (int j = 0; j < 4; ++j) {
      float p = __expf(sacc[kt][j] - mx);
      sacc[kt][j] = p;
      sum += p;
    }
  }
  sum += __shfl_xor(sum, 16);
  sum += __shfl_xor(sum, 32);
  lsum = sum;
  #pragma unroll
  for (int c = 0; c < MAXC; ++c) {
    if (c < nch) {
      u32 p00 = pkf16(sacc[2*c][0], sacc[2*c][1]);
      u32 p01 = pkf16(sacc[2*c][2], sacc[2*c][3]);
      u32 p10 = 0u, p11 = 0u;
      if (2*c + 1 < nkt) {
        p10 = pkf16(sacc[2*c+1][0], sacc[2*c+1][1]);
        p11 = pkf16(sacc[2*c+1][2], sacc[2*c+1][3]);
      }
      u32x4 w;
      #pragma unroll
      for (int wd = 0; wd < 4; ++wd) {
        int src = l15 + 16*((2*g + (wd >> 1)) & 3);
        u32 lo = (u32)__shfl((int)((wd & 1) ? p01 : p00), src, 64);
        u32 hi = (u32)__shfl((int)((wd & 1) ? p11 : p10), src, 64);
        w[wd] = (g >> 1) ? hi : lo;
      }
      pf[c] = w;
    }
  }
}

template<int MAXC>
__device__ __forceinline__ void out_sub_fb(int qt, const u32x4 (&pf)[MAXC], float lsum,
                                           const char* bufVT, const float* __restrict__ bvg,
                                           float* __restrict__ outb, int l15, int g) {
  const int nch = (qt + 2) >> 1;
  const float inv = 1.f / lsum;
  #pragma unroll
  for (int et = 0; et < 8; ++et) {
    f32x4 acc = {0.f, 0.f, 0.f, 0.f};
    #pragma unroll
    for (int c = 0; c < MAXC; ++c) {
      if (c < nch) {
        f16x8 aV = *(const f16x8*)(bufVT + offR512(et*16 + l15, 4*c + g));
        f16x8 pb = __builtin_bit_cast(f16x8, pf[c]);
        acc = mfma16(aV, pb, acc);
      }
    }
    const int q  = qt*16 + l15;
    const int e0 = et*16 + g*4;
    f32x4 bvv = *(const f32x4*)(bvg + e0);
    f32x4 o;
    #pragma unroll
    for (int j = 0; j < 4; ++j) o[j] = acc[j]*inv + bvv[j];
    *(f32x4*)(outb + q*DD + e0) = o;
  }
}

__global__ __launch_bounds__(512, 2)
void head_fused_fb(const float* __restrict__ x, const u16* __restrict__ MTg,
                   const u16* __restrict__ Wvg, const float* __restrict__ m0g,
                   const float* __restrict__ bvg, float* __restrict__ out) {
  extern __shared__ char lds[];
  char* bufX = lds;
  char* bufA = lds + 65536;
  char* bufW = lds + 131072;

  const int tid  = threadIdx.x;
  const int wave = tid >> 6;
  const int lane = tid & 63;
  const int l15  = lane & 15;
  const int g    = lane >> 4;
  const int b    = blockIdx.x;
  const float* xb = x + (size_t)b * (TT*DD);

  {
    u32x4* p = (u32x4*)lds;
    #pragma unroll
    for (int i = 0; i < 20; ++i) { u32x4 z = {0u,0u,0u,0u}; p[tid + i*512] = z; }
  }
  __syncthreads();

  #pragma unroll
  for (int i = 0; i < 8; ++i) {
    int chunk = tid + i*512;
    int row = chunk >> 4, c = chunk & 15;
    const float* p = xb + row*DD + c*8;
    f32x4 v0 = *(const f32x4*)p;
    f32x4 v1 = *(const f32x4*)(p + 4);
    u32x4 w;
    w[0] = pkf16(v0[0], v0[1]);
    w[1] = pkf16(v0[2], v0[3]);
    w[2] = pkf16(v1[0], v1[1]);
    w[3] = pkf16(v1[2], v1[3]);
    *(u32x4*)(bufX + offR256(row, c)) = w;
  }
  #pragma unroll
  for (int i = 0; i < 4; ++i) {
    int chunk = tid + i*512;
    int row = chunk >> 4, c = chunk & 15;
    u32x4 v = *(const u32x4*)((const char*)MTg + row*256 + c*16);
    *(u32x4*)(bufW + offR256(row, c)) = v;
  }
  __syncthreads();

  #pragma unroll
  for (int s = 0; s < 2; ++s) {
    const int qt = 2*wave + s;
    f16x8 aX[4];
    #pragma unroll
    for (int kc = 0; kc < 4; ++kc)
      aX[kc] = *(const f16x8*)(bufX + offR256(qt*16 + l15, 4*kc + g));
    #pragma unroll
    for (int nt = 0; nt < 8; ++nt) {
      f32x4 acc = {0.f, 0.f, 0.f, 0.f};
      #pragma unroll
      for (int kc = 0; kc < 4; ++kc) {
        f16x8 bM = *(const f16x8*)(bufW + offR256(nt*16 + l15, 4*kc + g));
        acc = mfma16(aX[kc], bM, acc);
      }
      float m0v = m0g[nt*16 + l15];
      #pragma unroll
      for (int j = 0; j < 4; ++j)
        *(u16*)(bufA + offR256h(qt*16 + g*4 + j, nt*16 + l15)) = tof16(acc[j] + m0v);
    }
  }
  __syncthreads();

  u32x4 pf0[4]; u32x4 pf1[8];
  float ls0, ls1;
  attn_sub_fb<8, 4>(wave,       pf0, ls0, bufX, bufA, l15, g);
  attn_sub_fb<16, 8>(15 - wave, pf1, ls1, bufX, bufA, l15, g);
  __syncthreads();

  #pragma unroll
  for (int i = 0; i < 4; ++i) {
    int chunk = tid + i*512;
    int row = chunk >> 4, c = chunk & 15;
    u32x4 v = *(const u32x4*)((const char*)Wvg + row*256 + c*16);
    *(u32x4*)(bufW + offR256(row, c)) = v;
  }
  __syncthreads();

  #pragma unroll
  for (int s = 0; s < 2; ++s) {
    const int kt = 2*wave + s;
    f16x8 bX[4];
    #pragma unroll
    for (int kc = 0; kc < 4; ++kc)
      bX[kc] = *(const f16x8*)(bufX + offR256(kt*16 + l15, 4*kc + g));
    #pragma unroll
    for (int et = 0; et < 8; ++et) {
      f32x4 acc = {0.f, 0.f, 0.f, 0.f};
      #pragma unroll
      for (int kc = 0; kc < 4; ++kc) {
        f16x8 aW = *(const f16x8*)(bufW + offR256(et*16 + l15, 4*kc + g));
        acc = mfma16(aW, bX[kc], acc);
      }
      #pragma unroll
      for (int j = 0; j < 4; ++j)
        *(u16*)(bufA + offR512h(et*16 + g*4 + j, kt*16 + l15)) = tof16(acc[j]);
    }
  }
  __syncthreads();

  float* outb = out + (size_t)b * (TT*DD);
  out_sub_fb<4>(wave,       pf0, ls0, bufA, bvg, outb, l15, g);
  out_sub_fb<8>(15 - wave,  pf1, ls1, bufA, bvg, outb, l15, g);
}

// ================= launcher =================
extern "C" void kernel_launch(void* const* d_in, const int* in_sizes, int n_in,
                              void* d_out, int out_size, void* d_ws, size_t ws_size,
                              hipStream_t stream) {
  (void)in_sizes; (void)n_in; (void)out_size;
  const float* x  = (const float*)d_in[0];
  const float* Wk = (const float*)d_in[1];
  // d_in[2] = bk: only per-q-row constants in scores -> dropped by softmax
  const float* Wq = (const float*)d_in[3];
  const float* bq = (const float*)d_in[4];
  const float* Wv = (const float*)d_in[5];
  const float* bv = (const float*)d_in[6];

  char* ws = (char*)d_ws;
  const size_t XH_BYTES = (size_t)512 * 65536;   // 33.5 MB
  const size_t VT_BYTES = (size_t)512 * 65536;   // 33.5 MB
  const size_t need = XH_BYTES + VT_BYTES + 65536 + 512;

  if (ws_size >= need) {
    char*  xhp = ws;
    char*  vtp = ws + XH_BYTES;
    char*  wts = ws + XH_BYTES + VT_BYTES;
    u16*   MT  = (u16*)wts;
    u16*   WvB = (u16*)(wts + 32768);
    float* m0  = (float*)(wts + 65536);

    precompute_k<<<128, 128, 0, stream>>>(Wk, Wq, bq, Wv, MT, WvB, m0);
    proj_vt<<<512, 256, 0, stream>>>(x, WvB, xhp, vtp);
    attn_k<<<2048, 256, 0, stream>>>(xhp, vtp, MT, m0, bv, (float*)d_out);
  } else {
    // fallback: verified round-2 fused kernel (160 KB LDS)
    u16*   MT  = (u16*)ws;
    u16*   WvB = (u16*)(ws + 32768);
    float* m0  = (float*)(ws + 65536);
    (void)hipFuncSetAttribute((const void*)head_fused_fb,
                              hipFuncAttributeMaxDynamicSharedMemorySize, 163840);
    precompute_k<<<128, 128, 0, stream>>>(Wk, Wq, bq, Wv, MT, WvB, m0);
    head_fused_fb<<<512, 512, 163840, stream>>>(x, MT, WvB, m0, bv, (float*)d_out);
  }
}

// Round 7
// 113.730 us; speedup vs baseline: 2.2220x; 1.0296x over previous
//
#include <hip/hip_runtime.h>
#include <hip/hip_fp16.h>

#define TT 256
#define DD 128
#define NEG -30000.0f

typedef __attribute__((ext_vector_type(4))) float f32x4;
typedef __attribute__((ext_vector_type(8))) _Float16 f16x8;
typedef unsigned int u32;
typedef __attribute__((ext_vector_type(4))) u32 u32x4;
typedef unsigned short u16;

__device__ __forceinline__ u16 tof16(float v) {
  return __builtin_bit_cast(u16, (_Float16)v);
}
__device__ __forceinline__ u32 pkf16(float lo, float hi) {
  return (u32)tof16(lo) | ((u32)tof16(hi) << 16);
}
__device__ __forceinline__ f32x4 mfma16(f16x8 a, f16x8 b, f32x4 c) {
  return __builtin_amdgcn_mfma_f32_16x16x32_f16(a, b, c, 0, 0, 0);
}

// D-layout -> operand-frag repack (verified rounds 2-6). src[2P] D-tiles
// (rows t*16+g*4+j, col l15) -> dst[P] frags: lane(l15,g) holds packed f16 of
// M[col=l15][row=p*32+g*8+0..7].
template<int P>
__device__ __forceinline__ void convN(const f32x4* src, u32x4* dst, int l15, int g) {
  #pragma unroll
  for (int p = 0; p < P; ++p) {
    u32 p00 = pkf16(src[2*p][0], src[2*p][1]);
    u32 p01 = pkf16(src[2*p][2], src[2*p][3]);
    u32 p10 = pkf16(src[2*p+1][0], src[2*p+1][1]);
    u32 p11 = pkf16(src[2*p+1][2], src[2*p+1][3]);
    u32x4 w;
    #pragma unroll
    for (int wd = 0; wd < 4; ++wd) {
      int srcl = l15 + 16*((2*g + (wd >> 1)) & 3);
      u32 lo = (u32)__shfl((int)((wd & 1) ? p01 : p00), srcl, 64);
      u32 hi = (u32)__shfl((int)((wd & 1) ? p11 : p10), srcl, 64);
      w[wd] = (g >> 1) ? hi : lo;
    }
    dst[p] = w;
  }
}

// ---------------- K1: half-batch blocks; Xh + VT frag-blocked to ws.
// Precompute (MT, m0) fused into blocks bid<128. XCD-matched swizzle: bid%8 == b%8.
// xh[b][kt][kc][g][l15]*16B ; vt[b][et][c][g][l15]*16B
__global__ __launch_bounds__(256, 4)
void proj_vt(const float* __restrict__ x, const float* __restrict__ Wq,
             const float* __restrict__ Wk, const float* __restrict__ bq,
             const float* __restrict__ Wv,
             char* __restrict__ xh, char* __restrict__ vt,
             u16* __restrict__ MT, float* __restrict__ m0) {
  const int tid = threadIdx.x;
  const int w = tid >> 6, lane = tid & 63, l15 = lane & 15, g = lane >> 4;
  const int bid = blockIdx.x;
  const int i2 = bid >> 3, r = bid & 7;
  const int b = ((i2 >> 1) << 3) | r;     // b % 8 == bid % 8  (same XCD as attn)
  const int h = i2 & 1;                   // half of the batch
  const float* xb = x + (size_t)b * (TT*DD);
  char* xhb = xh + (size_t)b * 65536;
  char* vtb = vt + (size_t)b * 65536;
  const int kt0 = h*8 + 2*w;              // this wave's 2 k-tiles

  // load + cvt X rows; store Xh frags; keep in regs for VT
  f16x8 bX[2][4];
  #pragma unroll
  for (int t = 0; t < 2; ++t) {
    const int kt = kt0 + t;
    #pragma unroll
    for (int kc = 0; kc < 4; ++kc) {
      const float* p = xb + (kt*16 + l15)*DD + kc*32 + g*8;
      f32x4 v0 = *(const f32x4*)p, v1 = *(const f32x4*)(p + 4);
      u32x4 pk;
      pk[0] = pkf16(v0[0], v0[1]); pk[1] = pkf16(v0[2], v0[3]);
      pk[2] = pkf16(v1[0], v1[1]); pk[3] = pkf16(v1[2], v1[3]);
      bX[t][kc] = __builtin_bit_cast(f16x8, pk);
      *(u32x4*)(xhb + kt*4096 + kc*1024 + g*256 + l15*16) = pk;
    }
  }

  // VT: V[k][e] = mfma(A = X rows k, B = Wv rows e); conv -> VT A-frags; store
  #pragma unroll
  for (int et = 0; et < 8; ++et) {
    f16x8 bWv[4];
    #pragma unroll
    for (int kc = 0; kc < 4; ++kc) {
      const float* p = Wv + (et*16 + l15)*DD + kc*32 + g*8;
      f32x4 v0 = *(const f32x4*)p, v1 = *(const f32x4*)(p + 4);
      u32x4 pk;
      pk[0] = pkf16(v0[0], v0[1]); pk[1] = pkf16(v0[2], v0[3]);
      pk[2] = pkf16(v1[0], v1[1]); pk[3] = pkf16(v1[2], v1[3]);
      bWv[kc] = __builtin_bit_cast(f16x8, pk);
    }
    f32x4 vacc[2];
    #pragma unroll
    for (int t = 0; t < 2; ++t) {
      f32x4 acc = {0.f, 0.f, 0.f, 0.f};
      #pragma unroll
      for (int kc = 0; kc < 4; ++kc) acc = mfma16(bX[t][kc], bWv[kc], acc);
      vacc[t] = acc;
    }
    u32x4 dv[1];
    convN<1>(vacc, dv, l15, g);
    *(u32x4*)(vtb + et*8192 + (h*4 + w)*1024 + g*256 + l15*16) = dv[0];
  }

  // fused precompute: MT[d'][d] = sum_e Wq[e][d]Wk[e][d']; m0[d] = sum_e bq[e]Wk[e][d]
  if (bid < 128) {
    const int dp = bid;
    if (tid < 128) {
      float acc = 0.f;
      for (int e = 0; e < DD; ++e) acc = fmaf(Wq[e*DD + tid], Wk[e*DD + dp], acc);
      MT[dp*DD + tid] = tof16(acc);
    }
    if (bid == 0 && tid >= 128) {
      const int d = tid - 128;
      float a0 = 0.f;
      for (int e = 0; e < DD; ++e) a0 = fmaf(bq[e], Wk[e*DD + d], a0);
      m0[d] = a0;
    }
  }
}

// ---------------- K2: attention, online softmax. 2048 blocks x 256 thr;
// wave = one q-tile; no LDS, no barriers; per-chunk S->softmax->pf->PV stream.
__global__ __launch_bounds__(256, 4)
void attn_k(const char* __restrict__ xh, const char* __restrict__ vt,
            const u16* __restrict__ MTg, const float* __restrict__ m0g,
            const float* __restrict__ bvg, float* __restrict__ out) {
  const int tid  = threadIdx.x;
  const int wave = tid >> 6, lane = tid & 63, l15 = lane & 15, g = lane >> 4;
  const int bid = blockIdx.x;
  const int i = bid >> 3, r = bid & 7;
  const int b = ((i >> 2) << 3) | r;      // b % 8 == bid % 8 (matches proj_vt)
  const int s = i & 3;
  const int qt  = wave*4 + s;
  const int nkt = qt + 1;
  const int nch = (nkt + 1) >> 1;
  const char* xhb = xh + (size_t)b * 65536;
  const char* vtb = vt + (size_t)b * 65536;

  // ---- Phase A: A'-strip in regs (D[d'][q]); conv -> B-frags bAw (verified)
  f16x8 bXq[4];
  #pragma unroll
  for (int kc = 0; kc < 4; ++kc)
    bXq[kc] = *(const f16x8*)(xhb + qt*4096 + kc*1024 + g*256 + l15*16);
  f32x4 Aacc[8];
  #pragma unroll
  for (int dt = 0; dt < 8; ++dt) {
    f32x4 acc = {0.f, 0.f, 0.f, 0.f};
    #pragma unroll
    for (int kc = 0; kc < 4; ++kc) {
      f16x8 aM = *(const f16x8*)(MTg + (dt*16 + l15)*DD + kc*32 + g*8);
      acc = mfma16(aM, bXq[kc], acc);
    }
    f32x4 m0v = *(const f32x4*)(m0g + dt*16 + g*4);
    #pragma unroll
    for (int j = 0; j < 4; ++j) acc[j] += m0v[j];
    Aacc[dt] = acc;
  }
  u32x4 bAw[4];
  convN<4>(Aacc, bAw, l15, g);

  // ---- Online chunk loop: chunk c = k-tiles {2c, 2c+1}
  f32x4 oacc[8];
  #pragma unroll
  for (int et = 0; et < 8; ++et) { f32x4 z = {0.f,0.f,0.f,0.f}; oacc[et] = z; }
  float m = NEG, sum = 0.f;

  #pragma unroll
  for (int c = 0; c < 8; ++c) {
    if (c < nch) {
      // S tiles (D[k][q]) for kt=2c and (if valid) kt=2c+1; diagonal mask
      f32x4 s0, s1 = {NEG, NEG, NEG, NEG};
      {
        const int kt = 2*c;
        f32x4 acc = {0.f, 0.f, 0.f, 0.f};
        #pragma unroll
        for (int kc = 0; kc < 4; ++kc) {
          f16x8 aX = *(const f16x8*)(xhb + kt*4096 + kc*1024 + g*256 + l15*16);
          acc = mfma16(aX, __builtin_bit_cast(f16x8, bAw[kc]), acc);
        }
        if (kt == qt) {
          #pragma unroll
          for (int j = 0; j < 4; ++j)
            if (g*4 + j > l15) acc[j] = NEG;
        }
        s0 = acc;
      }
      if (2*c + 1 < nkt) {
        const int kt = 2*c + 1;
        f32x4 acc = {0.f, 0.f, 0.f, 0.f};
        #pragma unroll
        for (int kc = 0; kc < 4; ++kc) {
          f16x8 aX = *(const f16x8*)(xhb + kt*4096 + kc*1024 + g*256 + l15*16);
          acc = mfma16(aX, __builtin_bit_cast(f16x8, bAw[kc]), acc);
        }
        if (kt == qt) {
          #pragma unroll
          for (int j = 0; j < 4; ++j)
            if (g*4 + j > l15) acc[j] = NEG;
        }
        s1 = acc;
      }
      // running max (row = q = l15 across the 4 g-groups), defer-rescale THR=8
      float pmax = NEG;
      #pragma unroll
      for (int j = 0; j < 4; ++j) pmax = fmaxf(pmax, fmaxf(s0[j], s1[j]));
      pmax = fmaxf(pmax, __shfl_xor(pmax, 16));
      pmax = fmaxf(pmax, __shfl_xor(pmax, 32));
      if (!__all(pmax <= m + 8.f)) {
        float mn = fmaxf(m, pmax);
        float f  = __expf(m - mn);       // 0 on first chunk (m=NEG)
        sum *= f;
        #pragma unroll
        for (int et = 0; et < 8; ++et) {
          #pragma unroll
          for (int j = 0; j < 4; ++j) oacc[et][j] *= f;
        }
        m = mn;
      }
      #pragma unroll
      for (int j = 0; j < 4; ++j) {
        float p0 = __expf(s0[j] - m); s0[j] = p0; sum += p0;
        float p1 = __expf(s1[j] - m); s1[j] = p1; sum += p1;   // 0 if kt invalid
      }
      // pf chunk: P^T regs -> B-frag (lane: P[k=c*32+g*8+0..7][q=l15])
      u32 p00 = pkf16(s0[0], s0[1]);
      u32 p01 = pkf16(s0[2], s0[3]);
      u32 p10 = pkf16(s1[0], s1[1]);
      u32 p11 = pkf16(s1[2], s1[3]);
      u32x4 pw;
      #pragma unroll
      for (int wd = 0; wd < 4; ++wd) {
        int srcl = l15 + 16*((2*g + (wd >> 1)) & 3);
        u32 lo = (u32)__shfl((int)((wd & 1) ? p01 : p00), srcl, 64);
        u32 hi = (u32)__shfl((int)((wd & 1) ? p11 : p10), srcl, 64);
        pw[wd] = (g >> 1) ? hi : lo;
      }
      f16x8 pb = __builtin_bit_cast(f16x8, pw);
      // PV accumulate: O^T[e][q] += VT(et,c) . pb
      #pragma unroll
      for (int et = 0; et < 8; ++et) {
        f16x8 aV = *(const f16x8*)(vtb + et*8192 + c*1024 + g*256 + l15*16);
        oacc[et] = mfma16(aV, pb, oacc[et]);
      }
    }
  }

  // ---- epilogue: normalize + bv; store (verified layout)
  sum += __shfl_xor(sum, 16);
  sum += __shfl_xor(sum, 32);
  const float inv = 1.f / sum;
  float* outb = out + (size_t)b * (TT*DD);
  #pragma unroll
  for (int et = 0; et < 8; ++et) {
    f32x4 bvv = *(const f32x4*)(bvg + et*16 + g*4);
    f32x4 o;
    #pragma unroll
    for (int j = 0; j < 4; ++j) o[j] = oacc[et][j]*inv + bvv[j];
    *(f32x4*)(outb + (qt*16 + l15)*DD + et*16 + g*4) = o;
  }
}

// ================= launcher =================
extern "C" void kernel_launch(void* const* d_in, const int* in_sizes, int n_in,
                              void* d_out, int out_size, void* d_ws, size_t ws_size,
                              hipStream_t stream) {
  (void)in_sizes; (void)n_in; (void)out_size; (void)ws_size;
  const float* x  = (const float*)d_in[0];
  const float* Wk = (const float*)d_in[1];
  // d_in[2] = bk: only per-q-row constants in scores -> dropped by softmax
  const float* Wq = (const float*)d_in[3];
  const float* bq = (const float*)d_in[4];
  const float* Wv = (const float*)d_in[5];
  const float* bv = (const float*)d_in[6];

  char* ws = (char*)d_ws;
  const size_t XH_BYTES = (size_t)512 * 65536;   // 33.5 MB
  const size_t VT_BYTES = (size_t)512 * 65536;   // 33.5 MB
  char*  xhp = ws;
  char*  vtp = ws + XH_BYTES;
  char*  wts = ws + XH_BYTES + VT_BYTES;
  u16*   MT  = (u16*)wts;                        // 32 KB
  float* m0  = (float*)(wts + 32768);            // 512 B

  proj_vt<<<1024, 256, 0, stream>>>(x, Wq, Wk, bq, Wv, xhp, vtp, MT, m0);
  attn_k<<<2048, 256, 0, stream>>>(xhp, vtp, MT, m0, bv, (float*)d_out);
}